// Round 8
// baseline (30436.234 us; speedup 1.0000x reference)
//
#include <hip/hip_runtime.h>
#include <hip/hip_cooperative_groups.h>

namespace cg = cooperative_groups;

// HyperLSTM + MDN decoder — f32 in / f32 out (verified R5/R6, absmax 7.8e-3).
// R8: persistent cooperative kernel, grid 256x512 (1 block/CU guaranteed
// co-resident; R7's 512-block/2-per-CU launch was rejected by the runtime).
// Per-block fixed weight column slices -> each weight byte read once/step,
// XCD-L2 resident. Wave-uniform weight reads (s_load), lane=batch coalesced
// activation reads. 4 grid.sync per step.
#define NSEQ 128

__device__ float g_hT  [1024 * 64];
__device__ float g_cT  [1024 * 64];
__device__ float g_hhT [256 * 64];
__device__ float g_chT [256 * 64];
__device__ float g_gT  [1024 * 64];   // hyper pre-gates
__device__ float g_hWhT[4096 * 64];
__device__ float g_xWxT[4096 * 64];
__device__ float g_zT  [768 * 64];    // zx(256)|zh(256)|zb(256)
__device__ float g_xT  [133 * 64];    // current x_t transposed
__device__ float g_penT[3 * 64];      // raw pen logits for t-1

__device__ __forceinline__ float sigf(float x) { return 1.0f / (1.0f + expf(-x)); }

__global__ __launch_bounds__(512, 2) void mega_kernel(
    const float* __restrict__ z,        const float* __restrict__ strokes,
    const float* __restrict__ fc_in_w,  const float* __restrict__ fc_in_b,
    const float* __restrict__ fc_proj_w,const float* __restrict__ fc_proj_b,
    const float* __restrict__ Wx,       const float* __restrict__ Wh,
    const float* __restrict__ b0w,
    const float* __restrict__ Wxh_hy,   const float* __restrict__ Whh_hy,
    const float* __restrict__ b_hy,
    const float* __restrict__ Wzx,      const float* __restrict__ bzx,
    const float* __restrict__ Wzh,      const float* __restrict__ bzh,
    const float* __restrict__ Wzb,
    const float* __restrict__ Dx,       const float* __restrict__ Dh,
    const float* __restrict__ Db,       float* __restrict__ out)
{
    cg::grid_group grid = cg::this_grid();
    const int blk = blockIdx.x, tid = threadIdx.x;
    const int b = tid & 63, w = tid >> 6;        // lane-batch, wave 0..7

    __shared__ float part  [8192];   // 32 KB: Wh / xWx partials (reused)
    __shared__ float part_g[2048];   //  8 KB: gate / z partials
    __shared__ float part_p[512];    //  2 KB: proj partials
    __shared__ float pre_l [1024];   //  4 KB: P4 pre[g][hcl][b]

    // ================= init: s0 = tanh(z @ fc_in_w + b) =================
    for (int i = tid; i < 8192; i += 512)                 // z^T into LDS
        part[i] = z[(i & 63) * 128 + (i >> 6)];
    __syncthreads();
    for (int n = tid; n < 640; n += 512) {                // 256 blk * 640 = 163840
        int item = blk * 640 + n, j = item >> 6, bb = item & 63;
        float acc = fc_in_b[j];
        #pragma unroll 4
        for (int k = 0; k < 128; k++) acc += part[k * 64 + bb] * fc_in_w[k * 2560 + j];
        float s = tanhf(acc);
        if      (j < 1024) g_hT [j * 64 + bb]          = s;
        else if (j < 2048) g_cT [(j - 1024) * 64 + bb] = s;
        else if (j < 2304) g_hhT[(j - 2048) * 64 + bb] = s;
        else               g_chT[(j - 2304) * 64 + bb] = s;
    }
    if (blk >= 224 && blk < 241) {                        // x^T(0)
        int idx = (blk - 224) * 512 + tid;
        if (idx < 8512) g_xT[idx] = strokes[(idx & 63) * 133 + (idx >> 6)];
    }
    grid.sync();

    // ================= main loop =================
    for (int t = 0; t <= NSEQ; t++) {
        const int c0 = blk * 16, gc0 = blk * 4;
        // -------- P1: hWh, xWx, gates; proj(t-1) --------
        if (t < NSEQ) {
            float accW[16], accG[4];
            #pragma unroll
            for (int ci = 0; ci < 16; ci++) accW[ci] = 0.f;
            accG[0] = accG[1] = accG[2] = accG[3] = 0.f;
            for (int k = w * 128; k < w * 128 + 128; k++) {
                float hv = g_hT[k * 64 + b];
                const float* wr = Wh + k * 4096 + c0;
                #pragma unroll
                for (int ci = 0; ci < 16; ci++) accW[ci] += hv * wr[ci];
                const float* gr = Wxh_hy + (133 + k) * 1024 + gc0;
                #pragma unroll
                for (int j = 0; j < 4; j++) accG[j] += hv * gr[j];
            }
            if (w < 4) {                                  // gate x-part
                int k0 = w * 34, k1 = (k0 + 34 < 133) ? k0 + 34 : 133;
                for (int k = k0; k < k1; k++) {
                    float xv = g_xT[k * 64 + b];
                    const float* gr = Wxh_hy + k * 1024 + gc0;
                    #pragma unroll
                    for (int j = 0; j < 4; j++) accG[j] += xv * gr[j];
                }
            } else {                                      // gate hh-part
                int k0 = (w - 4) * 64;
                for (int k = k0; k < k0 + 64; k++) {
                    float hhv = g_hhT[k * 64 + b];
                    const float* gr = Whh_hy + k * 1024 + gc0;
                    #pragma unroll
                    for (int j = 0; j < 4; j++) accG[j] += hhv * gr[j];
                }
            }
            #pragma unroll
            for (int ci = 0; ci < 16; ci++) part[(ci * 8 + w) * 64 + b] = accW[ci];
            #pragma unroll
            for (int j = 0; j < 4; j++) part_g[(j * 8 + w) * 64 + b] = accG[j];
            __syncthreads();
            for (int n = tid; n < 1024; n += 512) {
                int ci = n >> 6, bb = n & 63; float s = 0.f;
                #pragma unroll
                for (int u = 0; u < 8; u++) s += part[(ci * 8 + u) * 64 + bb];
                g_hWhT[(c0 + ci) * 64 + bb] = s;
            }
            if (tid < 256) {
                int j = tid >> 6, bb = tid & 63; float s = 0.f;
                #pragma unroll
                for (int u = 0; u < 8; u++) s += part_g[(j * 8 + u) * 64 + bb];
                g_gT[(gc0 + j) * 64 + bb] = s + b_hy[gc0 + j];
            }
            __syncthreads();
            float accX[16];
            #pragma unroll
            for (int ci = 0; ci < 16; ci++) accX[ci] = 0.f;
            int k0 = w * 17, k1 = (k0 + 17 < 133) ? k0 + 17 : 133;
            for (int k = k0; k < k1; k++) {
                float xv = g_xT[k * 64 + b];
                const float* wr = Wx + k * 4096 + c0;
                #pragma unroll
                for (int ci = 0; ci < 16; ci++) accX[ci] += xv * wr[ci];
            }
            #pragma unroll
            for (int ci = 0; ci < 16; ci++) part[(ci * 8 + w) * 64 + b] = accX[ci];
            __syncthreads();
            for (int n = tid; n < 1024; n += 512) {
                int ci = n >> 6, bb = n & 63; float s = 0.f;
                #pragma unroll
                for (int u = 0; u < 8; u++) s += part[(ci * 8 + u) * 64 + bb];
                g_xWxT[(c0 + ci) * 64 + bb] = s;
            }
        }
        if (t > 0 && blk < 123) {                         // proj col=blk, tp=t-1
            float accP = 0.f;
            #pragma unroll 4
            for (int k = w * 128; k < w * 128 + 128; k++)
                accP += g_hT[k * 64 + b] * fc_proj_w[k * 123 + blk];
            part_p[w * 64 + b] = accP;
            __syncthreads();
            if (tid < 64) {
                float acc = fc_proj_b[blk];
                #pragma unroll
                for (int u = 0; u < 8; u++) acc += part_p[u * 64 + b];
                int tp = t - 1, col = blk;
                if (col < 120) {
                    int m = col / 6, jj = col - m * 6;
                    int oidx = tp * 1280 + m * 64 + b;
                    if      (jj == 0) out[oidx]          = 1.0f;
                    else if (jj == 1) out[163840 + oidx] = acc;
                    else if (jj == 2) out[327680 + oidx] = acc;
                    else if (jj == 3) out[491520 + oidx] = expf(acc);
                    else if (jj == 4) out[655360 + oidx] = expf(acc);
                    else              out[819200 + oidx] = tanhf(acc);
                } else {
                    g_penT[(col - 120) * 64 + b] = acc;
                }
            }
        }
        grid.sync();   // s1

        // -------- P2: pen(t-1); hh/ch update; x(t+1) stage --------
        if (t > 0 && blk == 200 && tid < 64) {
            float v0 = g_penT[b], v1 = g_penT[64 + b], v2 = g_penT[128 + b];
            float mx = fmaxf(v0, fmaxf(v1, v2));
            float e0 = expf(v0 - mx), e1 = expf(v1 - mx), e2 = expf(v2 - mx);
            float s = e0 + e1 + e2;
            int base = 983040 + (t - 1) * 192 + b * 3;
            out[base] = e0 / s; out[base + 1] = e1 / s; out[base + 2] = e2 / s;
        }
        if (t == NSEQ) break;
        if (blk < 32) {
            int item = blk * 512 + tid, feat = item >> 6, bb = item & 63;
            float gi = g_gT[feat * 64 + bb],         gf = g_gT[(256 + feat) * 64 + bb];
            float gg = g_gT[(512 + feat) * 64 + bb], go = g_gT[(768 + feat) * 64 + bb];
            float chv = g_chT[feat * 64 + bb];
            chv = sigf(gf) * chv + sigf(gi) * tanhf(gg);
            float hhv = sigf(go) * tanhf(chv);
            g_chT[feat * 64 + bb] = chv;
            g_hhT[feat * 64 + bb] = hhv;
        } else if (blk >= 224 && blk < 241 && t + 1 < NSEQ) {
            int idx = (blk - 224) * 512 + tid;
            if (idx < 8512)
                g_xT[idx] = strokes[((t + 1) * 64 + (idx & 63)) * 133 + (idx >> 6)];
        }
        grid.sync();   // s2

        // -------- P3: z = hh' @ Wz* (+bias) --------
        {
            int zo0 = blk * 3;
            int zoA = zo0, zoB = zo0 + 1, zoC = zo0 + 2;
            const float* WA = (zoA < 256) ? Wzx : (zoA < 512) ? Wzh : Wzb;
            const float* WB = (zoB < 256) ? Wzx : (zoB < 512) ? Wzh : Wzb;
            const float* WC = (zoC < 256) ? Wzx : (zoC < 512) ? Wzh : Wzb;
            int oA = zoA & 255, oB = zoB & 255, oC = zoC & 255;
            float a0 = 0.f, a1 = 0.f, a2 = 0.f;
            for (int k = w * 32; k < w * 32 + 32; k++) {
                float hhv = g_hhT[k * 64 + b];
                a0 += hhv * WA[k * 256 + oA];
                a1 += hhv * WB[k * 256 + oB];
                a2 += hhv * WC[k * 256 + oC];
            }
            part_g[(0 * 8 + w) * 64 + b] = a0;
            part_g[(1 * 8 + w) * 64 + b] = a1;
            part_g[(2 * 8 + w) * 64 + b] = a2;
            __syncthreads();
            if (tid < 192) {
                int j = tid >> 6, bb = tid & 63, zo = zo0 + j;
                float s = 0.f;
                #pragma unroll
                for (int u = 0; u < 8; u++) s += part_g[(j * 8 + u) * 64 + bb];
                s += (zo < 256) ? bzx[zo] : (zo < 512) ? bzh[zo - 256] : 0.f;
                g_zT[zo * 64 + bb] = s;
            }
        }
        grid.sync();   // s3

        // -------- P4: einsums + combine + c/h update --------
        {
            int hc0 = blk * 4;
            #pragma unroll
            for (int pp = 0; pp < 2; pp++) {
                int p = w * 2 + pp, g = p >> 2, hcl = p & 3, h = hc0 + hcl;
                float sx = 0.f, sh = 0.f, sb = 0.f;
                int dbase = g * 65536 + h;
                int zbase = g * 4096 + b;     // (g*64+f)*64 + b
                #pragma unroll 4
                for (int f = 0; f < 64; f++) {
                    float zx = g_zT[zbase + f * 64];
                    float zh = g_zT[zbase + f * 64 + 16384];
                    float zb_ = g_zT[zbase + f * 64 + 32768];
                    int di = dbase + f * 1024;
                    sx += zx * Dx[di]; sh += zh * Dh[di]; sb += zb_ * Db[di];
                }
                float pre = sx * g_xWxT[(g * 1024 + h) * 64 + b]
                          + sh * g_hWhT[(g * 1024 + h) * 64 + b]
                          + sb + b0w[g * 1024 + h];
                pre_l[(g * 4 + hcl) * 64 + b] = pre;
            }
            __syncthreads();
            if (tid < 256) {
                int hcl = tid >> 6, bb = tid & 63, h = hc0 + hcl;
                float pi = pre_l[(0  + hcl) * 64 + bb];
                float pf = pre_l[(4  + hcl) * 64 + bb];
                float pg = pre_l[(8  + hcl) * 64 + bb];
                float po = pre_l[(12 + hcl) * 64 + bb];
                float cv = g_cT[h * 64 + bb];
                float nc = sigf(pf) * cv + sigf(pi) * tanhf(pg);
                float nh = sigf(po) * tanhf(nc);
                g_cT[h * 64 + bb] = nc;
                g_hT[h * 64 + bb] = nh;
            }
        }
        grid.sync();   // s4
    }
}

// ---------------------------------------------------------------------------
extern "C" void kernel_launch(void* const* d_in, const int* in_sizes, int n_in,
                              void* d_out, int out_size, void* d_ws, size_t ws_size,
                              hipStream_t stream)
{
    const float* z         = (const float*)d_in[0];
    const float* strokes   = (const float*)d_in[1];
    const float* fc_in_w   = (const float*)d_in[2];
    const float* fc_in_b   = (const float*)d_in[3];
    const float* fc_proj_w = (const float*)d_in[4];
    const float* fc_proj_b = (const float*)d_in[5];
    const float* Wx        = (const float*)d_in[6];
    const float* Wh        = (const float*)d_in[7];
    const float* b0w       = (const float*)d_in[8];
    const float* Wxh_hy    = (const float*)d_in[9];
    const float* Whh_hy    = (const float*)d_in[10];
    const float* b_hy      = (const float*)d_in[11];
    const float* Wzx       = (const float*)d_in[12];
    const float* bzx       = (const float*)d_in[13];
    const float* Wzh       = (const float*)d_in[14];
    const float* bzh       = (const float*)d_in[15];
    const float* Wzb       = (const float*)d_in[16];
    const float* Dx        = (const float*)d_in[17];
    const float* Dh        = (const float*)d_in[18];
    const float* Db        = (const float*)d_in[19];
    (void)d_ws; (void)ws_size;
    float* out = (float*)d_out;

    void* args[] = {
        (void*)&z, (void*)&strokes, (void*)&fc_in_w, (void*)&fc_in_b,
        (void*)&fc_proj_w, (void*)&fc_proj_b, (void*)&Wx, (void*)&Wh,
        (void*)&b0w, (void*)&Wxh_hy, (void*)&Whh_hy, (void*)&b_hy,
        (void*)&Wzx, (void*)&bzx, (void*)&Wzh, (void*)&bzh, (void*)&Wzb,
        (void*)&Dx, (void*)&Dh, (void*)&Db, (void*)&out
    };
    hipLaunchCooperativeKernel((const void*)mega_kernel,
                               dim3(256), dim3(512), args, 0, stream);
}